// Round 4
// baseline (1212.603 us; speedup 1.0000x reference)
//
#include <hip/hip_runtime.h>
#include <hip/hip_bf16.h>

// Problem constants (from reference)
#define N_NODES 16384
#define D_IN    128
#define D_H     64
#define BATCH   4096
#define CAP     1024   // LDS compaction capacity (true K ~= 128 per row)

typedef float fvec4 __attribute__((ext_vector_type(4)));

// ---------------------------------------------------------------------------
// Kernel 1: enc = X @ W + b   [N_NODES, D_H] fp32 into workspace.
// No LDS. Each wave owns 4 consecutive rows; row pointers are forced
// wave-uniform (readfirstlane) so X reads scalarize to s_load (SMEM pipe,
// SGPR operand feeds fmaf directly). W[d][h] is a coalesced 256B L1-hit
// vector load shared by all 4 accumulators. DS pipe: completely idle.
// ---------------------------------------------------------------------------
__global__ __launch_bounds__(256) void encoder_kernel(
    const float* __restrict__ X, const float* __restrict__ W,
    const float* __restrict__ b, float* __restrict__ enc)
{
    const int wave = __builtin_amdgcn_readfirstlane((int)(threadIdx.x >> 6));
    const int lane = threadIdx.x & 63;
    const int r0   = blockIdx.x * 16 + wave * 4;   // 16 rows/block, 4 rows/wave

    const float* __restrict__ x0 = X + (size_t)r0 * D_IN;
    const float* __restrict__ x1 = x0 + D_IN;
    const float* __restrict__ x2 = x1 + D_IN;
    const float* __restrict__ x3 = x2 + D_IN;

    float a0 = b[lane];
    float a1 = a0, a2 = a0, a3 = a0;

    #pragma unroll
    for (int d = 0; d < D_IN; ++d) {
        const float wv = W[d * D_H + lane];   // coalesced 256B, L1-hit after warmup
        a0 = fmaf(x0[d], wv, a0);             // x*[d] wave-uniform -> s_load/SGPR
        a1 = fmaf(x1[d], wv, a1);
        a2 = fmaf(x2[d], wv, a2);
        a3 = fmaf(x3[d], wv, a3);
    }

    float* __restrict__ o = enc + (size_t)r0 * D_H + lane;
    o[0 * D_H] = a0;                          // 4x coalesced 256B stores
    o[1 * D_H] = a1;
    o[2 * D_H] = a2;
    o[3 * D_H] = a3;
}

// ---------------------------------------------------------------------------
// Kernel 2: out[b][:] = ppr[idx[b]][:] @ enc
// One block per output row.
// Phase A: issue ALL 16 float4 loads per thread (64 KB/block in flight),
//          then compact nonzeros into LDS; per-register vmcnt waits give a
//          free software pipeline (consume in load order).
// Phase B: 4 wave-groups x 64 lanes, 4 independent accumulators (k-stride 16)
//          so 4 gather loads are concurrently outstanding; LDS-reduce.
// ---------------------------------------------------------------------------
__global__ __launch_bounds__(256) void diffuse_kernel(
    const float* __restrict__ ppr, const int* __restrict__ idx,
    const float* __restrict__ enc, float* __restrict__ out)
{
    __shared__ int   s_count;
    __shared__ int2  s_nz[CAP];      // {col, val bits} -> single b64 broadcast
    __shared__ float s_acc[4][D_H];

    const int brow = blockIdx.x;
    const int row  = idx[brow];

    if (threadIdx.x == 0) s_count = 0;
    __syncthreads();

    const fvec4* prow = (const fvec4*)(ppr + (size_t)row * N_NODES);

    // ---- Phase A ----
    fvec4 v[16];
    #pragma unroll
    for (int it = 0; it < 16; ++it)
        v[it] = __builtin_nontemporal_load(&prow[it * 256 + threadIdx.x]);

    #pragma unroll
    for (int it = 0; it < 16; ++it) {
        const int base = (it * 256 + threadIdx.x) * 4;
        const fvec4 w = v[it];
        if (w.x != 0.0f) { int p = atomicAdd(&s_count, 1); if (p < CAP) s_nz[p] = make_int2(base + 0, __float_as_int(w.x)); }
        if (w.y != 0.0f) { int p = atomicAdd(&s_count, 1); if (p < CAP) s_nz[p] = make_int2(base + 1, __float_as_int(w.y)); }
        if (w.z != 0.0f) { int p = atomicAdd(&s_count, 1); if (p < CAP) s_nz[p] = make_int2(base + 2, __float_as_int(w.z)); }
        if (w.w != 0.0f) { int p = atomicAdd(&s_count, 1); if (p < CAP) s_nz[p] = make_int2(base + 3, __float_as_int(w.w)); }
    }
    __syncthreads();

    // ---- Phase B ----
    const int K = min(s_count, CAP);
    const int g = threadIdx.x >> 6;   // wave-group 0..3
    const int h = threadIdx.x & 63;   // enc column

    float a0 = 0.0f, a1 = 0.0f, a2 = 0.0f, a3 = 0.0f;
    int k = g;
    for (; k + 12 < K; k += 16) {     // 4 independent gathers in flight
        const int2 n0 = s_nz[k];
        const int2 n1 = s_nz[k + 4];
        const int2 n2 = s_nz[k + 8];
        const int2 n3 = s_nz[k + 12];
        a0 = fmaf(__int_as_float(n0.y), enc[(size_t)n0.x * D_H + h], a0);
        a1 = fmaf(__int_as_float(n1.y), enc[(size_t)n1.x * D_H + h], a1);
        a2 = fmaf(__int_as_float(n2.y), enc[(size_t)n2.x * D_H + h], a2);
        a3 = fmaf(__int_as_float(n3.y), enc[(size_t)n3.x * D_H + h], a3);
    }
    for (; k < K; k += 4) {
        const int2 n0 = s_nz[k];
        a0 = fmaf(__int_as_float(n0.y), enc[(size_t)n0.x * D_H + h], a0);
    }
    s_acc[g][h] = (a0 + a1) + (a2 + a3);
    __syncthreads();

    if (g == 0) {
        out[(size_t)brow * D_H + h] =
            s_acc[0][h] + s_acc[1][h] + s_acc[2][h] + s_acc[3][h];
    }
}

extern "C" void kernel_launch(void* const* d_in, const int* in_sizes, int n_in,
                              void* d_out, int out_size, void* d_ws, size_t ws_size,
                              hipStream_t stream) {
    const float* X   = (const float*)d_in[0];   // [16384, 128]
    const float* ppr = (const float*)d_in[1];   // [16384, 16384]
    const float* W   = (const float*)d_in[2];   // [128, 64]
    const float* b   = (const float*)d_in[3];   // [64]
    const int*   idx = (const int*)d_in[4];     // [4096]
    float* out = (float*)d_out;                 // [4096, 64]

    float* enc = (float*)d_ws;                  // [16384, 64] = 4 MB scratch

    encoder_kernel<<<N_NODES / 16, 256, 0, stream>>>(X, W, b, enc);
    diffuse_kernel<<<BATCH, 256, 0, stream>>>(ppr, idx, enc, out);
}

// Round 5
// 1177.494 us; speedup vs baseline: 1.0298x; 1.0298x over previous
//
#include <hip/hip_runtime.h>
#include <hip/hip_bf16.h>

// Problem constants (from reference)
#define N_NODES 16384
#define D_IN    128
#define D_H     64
#define BATCH   4096
#define CAP     1024   // LDS compaction capacity (true K ~= 128 per row)

typedef float fvec4 __attribute__((ext_vector_type(4)));

// ---------------------------------------------------------------------------
// Kernel 1: enc = X @ W + b   [N_NODES, D_H] fp32 into workspace.
// 8 rows/block, 256 threads, 2 rows/thread. X rows staged in LDS and read
// back as float4 (ds_read_b128); W via L1.
// [R4 post-mortem: the no-LDS readfirstlane variant regressed — uniform-
//  address vector loads on the VMEM pipe beat neither the LDS broadcast nor
//  cross-wave reuse. This LDS version is the best measured.]
// ---------------------------------------------------------------------------
__global__ __launch_bounds__(256) void encoder_kernel(
    const float* __restrict__ X, const float* __restrict__ W,
    const float* __restrict__ b, float* __restrict__ enc)
{
    __shared__ float Xs[8][D_IN];   // 4 KB

    const int i0 = blockIdx.x * 8;
    // Stage 8 rows of X = 1024 floats = 256 float4: exactly one per thread.
    ((float4*)&Xs[0][0])[threadIdx.x] =
        ((const float4*)(X + (size_t)i0 * D_IN))[threadIdx.x];
    __syncthreads();

    const int rp = threadIdx.x >> 6;    // 0..3 -> rows 2rp, 2rp+1
    const int h  = threadIdx.x & 63;    // output column

    float acc0 = b[h];
    float acc1 = acc0;
    const float4* xs0 = (const float4*)&Xs[2 * rp][0];
    const float4* xs1 = (const float4*)&Xs[2 * rp + 1][0];
    #pragma unroll
    for (int d4 = 0; d4 < D_IN / 4; ++d4) {
        const float4 x0 = xs0[d4];      // ds_read_b128 broadcast
        const float4 x1 = xs1[d4];
        #pragma unroll
        for (int j = 0; j < 4; ++j) {
            const float wv = W[(d4 * 4 + j) * D_H + h];  // coalesced, L1-hit
            acc0 = fmaf(((const float*)&x0)[j], wv, acc0);
            acc1 = fmaf(((const float*)&x1)[j], wv, acc1);
        }
    }
    enc[(size_t)(i0 + 2 * rp)     * D_H + h] = acc0;
    enc[(size_t)(i0 + 2 * rp + 1) * D_H + h] = acc1;
}

// ---------------------------------------------------------------------------
// Kernel 2: out[b][:] = ppr[idx[b]][:] @ enc
// One block per output row.
// Phase A: issue ALL 16 float4 loads per thread (64 KB/block in flight),
//          then compact nonzeros into LDS; per-register vmcnt waits give a
//          free software pipeline (consume in load order).
// Phase B: 4 wave-groups x 64 lanes, 4 independent accumulators (k-stride 16)
//          so 4 gather loads are concurrently outstanding; LDS-reduce.
// ---------------------------------------------------------------------------
__global__ __launch_bounds__(256) void diffuse_kernel(
    const float* __restrict__ ppr, const int* __restrict__ idx,
    const float* __restrict__ enc, float* __restrict__ out)
{
    __shared__ int   s_count;
    __shared__ int2  s_nz[CAP];      // {col, val bits} -> single b64 broadcast
    __shared__ float s_acc[4][D_H];

    const int brow = blockIdx.x;
    const int row  = idx[brow];

    if (threadIdx.x == 0) s_count = 0;
    __syncthreads();

    const fvec4* prow = (const fvec4*)(ppr + (size_t)row * N_NODES);

    // ---- Phase A ----
    fvec4 v[16];
    #pragma unroll
    for (int it = 0; it < 16; ++it)
        v[it] = __builtin_nontemporal_load(&prow[it * 256 + threadIdx.x]);

    #pragma unroll
    for (int it = 0; it < 16; ++it) {
        const int base = (it * 256 + threadIdx.x) * 4;
        const fvec4 w = v[it];
        if (w.x != 0.0f) { int p = atomicAdd(&s_count, 1); if (p < CAP) s_nz[p] = make_int2(base + 0, __float_as_int(w.x)); }
        if (w.y != 0.0f) { int p = atomicAdd(&s_count, 1); if (p < CAP) s_nz[p] = make_int2(base + 1, __float_as_int(w.y)); }
        if (w.z != 0.0f) { int p = atomicAdd(&s_count, 1); if (p < CAP) s_nz[p] = make_int2(base + 2, __float_as_int(w.z)); }
        if (w.w != 0.0f) { int p = atomicAdd(&s_count, 1); if (p < CAP) s_nz[p] = make_int2(base + 3, __float_as_int(w.w)); }
    }
    __syncthreads();

    // ---- Phase B ----
    const int K = min(s_count, CAP);
    const int g = threadIdx.x >> 6;   // wave-group 0..3
    const int h = threadIdx.x & 63;   // enc column

    float a0 = 0.0f, a1 = 0.0f, a2 = 0.0f, a3 = 0.0f;
    int k = g;
    for (; k + 12 < K; k += 16) {     // 4 independent gathers in flight
        const int2 n0 = s_nz[k];
        const int2 n1 = s_nz[k + 4];
        const int2 n2 = s_nz[k + 8];
        const int2 n3 = s_nz[k + 12];
        a0 = fmaf(__int_as_float(n0.y), enc[(size_t)n0.x * D_H + h], a0);
        a1 = fmaf(__int_as_float(n1.y), enc[(size_t)n1.x * D_H + h], a1);
        a2 = fmaf(__int_as_float(n2.y), enc[(size_t)n2.x * D_H + h], a2);
        a3 = fmaf(__int_as_float(n3.y), enc[(size_t)n3.x * D_H + h], a3);
    }
    for (; k < K; k += 4) {
        const int2 n0 = s_nz[k];
        a0 = fmaf(__int_as_float(n0.y), enc[(size_t)n0.x * D_H + h], a0);
    }
    s_acc[g][h] = (a0 + a1) + (a2 + a3);
    __syncthreads();

    if (g == 0) {
        out[(size_t)brow * D_H + h] =
            s_acc[0][h] + s_acc[1][h] + s_acc[2][h] + s_acc[3][h];
    }
}

extern "C" void kernel_launch(void* const* d_in, const int* in_sizes, int n_in,
                              void* d_out, int out_size, void* d_ws, size_t ws_size,
                              hipStream_t stream) {
    const float* X   = (const float*)d_in[0];   // [16384, 128]
    const float* ppr = (const float*)d_in[1];   // [16384, 16384]
    const float* W   = (const float*)d_in[2];   // [128, 64]
    const float* b   = (const float*)d_in[3];   // [64]
    const int*   idx = (const int*)d_in[4];     // [4096]
    float* out = (float*)d_out;                 // [4096, 64]

    float* enc = (float*)d_ws;                  // [16384, 64] = 4 MB scratch

    encoder_kernel<<<N_NODES / 8, 256, 0, stream>>>(X, W, b, enc);
    diffuse_kernel<<<BATCH, 256, 0, stream>>>(ppr, idx, enc, out);
}